// Round 6
// baseline (222.079 us; speedup 1.0000x reference)
//
#include <hip/hip_runtime.h>
#include <stdint.h>

#define H_ 4
#define N_ 512
#define D_ 64
#define E_ (N_ * N_)        // 262144 edges per head
#define HE_ (H_ * E_)       // 1048576
#define EPS_ 1e-10f

// Partitionable threefry (verified rounds 1-5): counter (hi=0, lo=j), out = x0^x1.
__device__ __forceinline__ void tf2x32(unsigned x0, unsigned x1,
                                       unsigned& o0, unsigned& o1) {
  const unsigned ks0 = 0u;          // key hi of seed 42
  const unsigned ks1 = 42u;         // key lo
  const unsigned ks2 = 0x1BD11BDAu ^ ks0 ^ ks1;
  x0 += ks0; x1 += ks1;
#define TFR(r) { x0 += x1; x1 = (x1 << (r)) | (x1 >> (32 - (r))); x1 ^= x0; }
  TFR(13) TFR(15) TFR(26) TFR(6)
  x0 += ks1; x1 += ks2 + 1u;
  TFR(17) TFR(29) TFR(16) TFR(24)
  x0 += ks2; x1 += ks0 + 2u;
  TFR(13) TFR(15) TFR(26) TFR(6)
  x0 += ks0; x1 += ks1 + 3u;
  TFR(17) TFR(29) TFR(16) TFR(24)
  x0 += ks1; x1 += ks2 + 4u;
  TFR(13) TFR(15) TFR(26) TFR(6)
  x0 += ks2; x1 += ks0 + 5u;
#undef TFR
  o0 = x0; o1 = x1;
}

__device__ __forceinline__ unsigned rng_bits(unsigned j) {
  unsigned a, b;
  tf2x32(0u, j, a, b);
  return a ^ b;
}

__device__ __forceinline__ float u01(unsigned bits) {
  return __uint_as_float((bits >> 9) | 0x3f800000u) - 1.0f;
}

// ---------------- node projection + zero-init of control words
// ctrl layout: [0..3]=cnt per head, [4..7]=done0, [8..11]=done1
__global__ __launch_bounds__(256) void precompute_ab(
    const float* __restrict__ feats, const float* __restrict__ W_out,
    float* __restrict__ A, float* __restrict__ B, unsigned* __restrict__ ctrl) {
  int row = blockIdx.x * 4 + (threadIdx.x >> 6);   // h*N + n
  int d = threadIdx.x & 63;
  if (blockIdx.x == 0 && threadIdx.x < 12) ctrl[threadIdx.x] = 0u;
  __shared__ float f[4][64];
  f[threadIdx.x >> 6][d] = feats[row * D_ + d];
  __syncthreads();
  const float* fr = f[threadIdx.x >> 6];
  float a = 0.f, b = 0.f;
#pragma unroll 8
  for (int k = 0; k < D_; ++k) {
    float fv = fr[k];
    a = fmaf(fv, W_out[k * D_ + d], a);          // sender rows [0,64)
    b = fmaf(fv, W_out[(k + D_) * D_ + d], b);   // receiver rows [64,128)
  }
  A[row * D_ + d] = a;
  B[row * D_ + d] = b;
}

// ---------------- fused edge + topk: 64x16 tiles, all 1024 blocks co-resident
// (256 threads, 4 waves/EU requested, 26 KB LDS -> exactly 4 blocks/CU).
// Rendezvous idiom (syncthreads; t0: fence+atomicAdd; reader: fence after count)
// is the same sequence proven for cross-XCD cand[] traffic in rounds 3/5.
__global__ __launch_bounds__(256, 4) void edge_topk(
    const float* __restrict__ A, const float* __restrict__ B,
    const float* __restrict__ b_out, const float* __restrict__ W_cat,
    const float* __restrict__ b_cat, float* __restrict__ out,
    unsigned long long* __restrict__ blockmax,
    unsigned long long* __restrict__ cand, unsigned* __restrict__ ctrl) {
  __shared__ __align__(16) float Ash[64][68];   // stride 68: rows 16B-aligned
  __shared__ __align__(16) float Bsh[16][64];
  __shared__ float4 bsh4[16];
  __shared__ float4 wc4[32];
  __shared__ float bc2[2];
  __shared__ unsigned long long wmax[4];
  __shared__ unsigned long long sortk[512];     // threshold phase uses [0,256)
  __shared__ unsigned long long thrS;

  const int t = threadIdx.x;
  const int h = blockIdx.z;
  const int snd_base = blockIdx.x * 64;
  const int rec_base = blockIdx.y * 16;
  const int bm_idx = blockIdx.y * 8 + blockIdx.x;    // 0..255 within head
  unsigned* cnt = ctrl;              // [h]
  unsigned* done0 = ctrl + 4;        // [h]
  unsigned* done1 = ctrl + 8;        // [h]

  {
    const float4* A4 = (const float4*)(A + (h * N_ + snd_base) * D_);
    for (int i = t; i < 1024; i += 256)          // 64 rows x 16 float4
      *(float4*)&Ash[i >> 4][(i & 15) << 2] = A4[i];
    const float4* B4 = (const float4*)(B + (h * N_ + rec_base) * D_);
    *(float4*)&Bsh[t >> 4][(t & 15) << 2] = B4[t];
  }
  if (t < 16) bsh4[t] = ((const float4*)b_out)[t];
  else if (t < 48) wc4[t - 16] = ((const float4*)W_cat)[t - 16];
  else if (t == 48) { bc2[0] = b_cat[0]; bc2[1] = b_cat[1]; }
  __syncthreads();

  const int s = t & 63;            // sender lane (per-lane varying)
  const int rg = (t >> 6) * 4;     // receiver group (wave-uniform)

  float l0[4], l1[4];
#pragma unroll
  for (int r = 0; r < 4; ++r) { l0[r] = 0.f; l1[r] = 0.f; }

  // Per edge the fp chain is EXACTLY: for d=0..63 { t=relu((A+B)+b); l=fma(t,w,l) }
#pragma unroll
  for (int d4 = 0; d4 < 16; ++d4) {
    const float4 a0 = *(const float4*)&Ash[s][d4 << 2];
    const float4 bd = bsh4[d4];
    const float4 wA = wc4[2 * d4];
    const float4 wB = wc4[2 * d4 + 1];
#pragma unroll
    for (int r = 0; r < 4; ++r) {
      const float4 bv = *(const float4*)&Bsh[rg + r][d4 << 2];
      float t0;
      t0 = fmaxf((a0.x + bv.x) + bd.x, 0.f);
      l0[r] = fmaf(t0, wA.x, l0[r]); l1[r] = fmaf(t0, wA.y, l1[r]);
      t0 = fmaxf((a0.y + bv.y) + bd.y, 0.f);
      l0[r] = fmaf(t0, wA.z, l0[r]); l1[r] = fmaf(t0, wA.w, l1[r]);
      t0 = fmaxf((a0.z + bv.z) + bd.z, 0.f);
      l0[r] = fmaf(t0, wB.x, l0[r]); l1[r] = fmaf(t0, wB.y, l1[r]);
      t0 = fmaxf((a0.w + bv.w) + bd.w, 0.f);
      l0[r] = fmaf(t0, wB.z, l0[r]); l1[r] = fmaf(t0, wB.w, l1[r]);
    }
  }

  unsigned long long ekey[4];
  unsigned long long mk = 0ull;
#pragma unroll
  for (int r = 0; r < 4; ++r) {
    float L0 = l0[r] + bc2[0];
    float L1 = l1[r] + bc2[1];
    const unsigned snd = (unsigned)(snd_base + s);
    const unsigned rec = (unsigned)(rec_base + rg + r);
    const unsigned e = rec * (unsigned)N_ + snd;
    const unsigned base = ((unsigned)h << 18) + e;
    const unsigned j0 = base * 2u;

    float uu0 = u01(rng_bits(j0));
    float uu1 = u01(rng_bits(j0 + 1u));
    float g0 = -logf(-logf(uu0 + EPS_) + EPS_);
    float g1 = -logf(-logf(uu1 + EPS_) + EPS_);

    // argmax(softmax((l+g)/0.5)) == (L1+g1 > L0+g0): /0.5 exact, softmax monotone
    float cm = ((L1 + g1) > (L0 + g0)) ? 1.0f : 0.0f;

    float lm = fmaxf(L0, L1);
    float p0 = expf(L0 - lm), p1 = expf(L1 - lm);
    float pr = p1 / (p0 + p1);

    out[base] = cm;
    out[HE_ + base] = pr;

    unsigned long long key =
        ((unsigned long long)__float_as_uint(pr) << 32) | (unsigned)(~e);
    ekey[r] = key;
    mk = key > mk ? key : mk;
  }

  // vectorized zero of this tile's sparse region (16 rows x 64 cols, disjoint 256B)
  {
    const float4 z4 = {0.f, 0.f, 0.f, 0.f};
    *(float4*)&out[2u * HE_ + ((unsigned)h << 18) +
                   (unsigned)(rec_base + (t >> 4)) * N_ + (unsigned)snd_base +
                   ((unsigned)(t & 15) << 2)] = z4;
  }

#pragma unroll
  for (int off = 32; off; off >>= 1) {
    unsigned long long o = __shfl_xor(mk, off, 64);
    mk = o > mk ? o : mk;
  }
  if ((t & 63) == 0) wmax[t >> 6] = mk;
  __syncthreads();                 // all stores issued; wmax ready
  if (t == 0) {
    unsigned long long mx = wmax[0];
#pragma unroll
    for (int i = 1; i < 4; ++i) mx = wmax[i] > mx ? wmax[i] : mx;
    blockmax[h * 256 + bm_idx] = mx;
    __threadfence();                               // release out/blockmax
    atomicAdd(&done0[h], 1u);
    while (atomicAdd(&done0[h], 0u) < 256u) __builtin_amdgcn_s_sleep(2);
    __threadfence();                               // acquire
  }
  __syncthreads();

  // threshold = 64th-largest of the 256 chunk maxes (keys unique -> exact)
  sortk[t] = blockmax[h * 256 + t];
  __syncthreads();
  {
    unsigned long long my = sortk[t];
    int rank = 0;
    for (int j = 0; j < 256; ++j) rank += (sortk[j] > my);
    if (rank == 63) thrS = my;     // <= true 64th-largest key; >=64 keys pass
  }
  __syncthreads();
  const unsigned long long thr = thrS;

  // compact from registers (expected ~155/head << 512)
#pragma unroll
  for (int r = 0; r < 4; ++r) {
    if (ekey[r] >= thr) {
      unsigned pos = atomicAdd(&cnt[h], 1u);
      if (pos < 512u) cand[h * 512 + pos] = ekey[r];
    }
  }
  __syncthreads();
  if (t == 0) { __threadfence(); atomicAdd(&done1[h], 1u); }   // release cand

  // finisher block per head: sort candidates, scatter 64 ones
  if (bm_idx == 0) {
    if (t == 0) {
      while (atomicAdd(&done1[h], 0u) < 256u) __builtin_amdgcn_s_sleep(2);
      __threadfence();                             // acquire
    }
    __syncthreads();
    unsigned n = atomicAdd(&cnt[h], 0u);
    if (n > 512u) n = 512u;
    sortk[t] = (t < (int)n) ? cand[h * 512 + t] : 0ull;
    sortk[t + 256] = (t + 256 < (int)n) ? cand[h * 512 + t + 256] : 0ull;
    __syncthreads();
    for (int k = 2; k <= 512; k <<= 1)
      for (int j = k >> 1; j > 0; j >>= 1) {
#pragma unroll
        for (int half = 0; half < 2; ++half) {
          int idx = t + half * 256;
          int ixj = idx ^ j;
          if (ixj > idx) {                         // each pair handled exactly once
            unsigned long long x = sortk[idx], y = sortk[ixj];
            bool up = (idx & k) == 0;
            if ((x > y) == up) { sortk[idx] = y; sortk[ixj] = x; }
          }
        }
        __syncthreads();
      }
    if (t >= 192) {                                // ascending: top 64 at [448,512)
      unsigned e = ~(unsigned)(sortk[t + 256] & 0xFFFFFFFFull);
      if (e < (unsigned)E_) out[2u * HE_ + ((unsigned)h << 18) + e] = 1.0f;
    }
  }
}

extern "C" void kernel_launch(void* const* d_in, const int* in_sizes, int n_in,
                              void* d_out, int out_size, void* d_ws, size_t ws_size,
                              hipStream_t stream) {
  const float* feats = (const float*)d_in[0];
  const float* W_out = (const float*)d_in[1];
  const float* b_out = (const float*)d_in[2];
  const float* W_cat = (const float*)d_in[3];
  const float* b_cat = (const float*)d_in[4];
  float* out = (float*)d_out;

  // workspace: A | B | blockmax | cand | ctrl(12 words)
  float* A = (float*)d_ws;
  float* B = A + H_ * N_ * D_;
  unsigned long long* blockmax = (unsigned long long*)(B + H_ * N_ * D_);
  unsigned long long* cand = blockmax + H_ * 256;
  unsigned* ctrl = (unsigned*)(cand + H_ * 512);

  precompute_ab<<<dim3(H_ * N_ / 4), dim3(256), 0, stream>>>(feats, W_out, A, B,
                                                             ctrl);
  edge_topk<<<dim3(N_ / 64, N_ / 16, H_), dim3(256), 0, stream>>>(
      A, B, b_out, W_cat, b_cat, out, blockmax, cand, ctrl);
}

// Round 7
// 107.858 us; speedup vs baseline: 2.0590x; 2.0590x over previous
//
#include <hip/hip_runtime.h>
#include <stdint.h>

#define H_ 4
#define N_ 512
#define D_ 64
#define E_ (N_ * N_)        // 262144 edges per head
#define HE_ (H_ * E_)       // 1048576
#define EPS_ 1e-10f

// Partitionable threefry (verified rounds 1-6): counter (hi=0, lo=j), out = x0^x1.
__device__ __forceinline__ void tf2x32(unsigned x0, unsigned x1,
                                       unsigned& o0, unsigned& o1) {
  const unsigned ks0 = 0u;          // key hi of seed 42
  const unsigned ks1 = 42u;         // key lo
  const unsigned ks2 = 0x1BD11BDAu ^ ks0 ^ ks1;
  x0 += ks0; x1 += ks1;
#define TFR(r) { x0 += x1; x1 = (x1 << (r)) | (x1 >> (32 - (r))); x1 ^= x0; }
  TFR(13) TFR(15) TFR(26) TFR(6)
  x0 += ks1; x1 += ks2 + 1u;
  TFR(17) TFR(29) TFR(16) TFR(24)
  x0 += ks2; x1 += ks0 + 2u;
  TFR(13) TFR(15) TFR(26) TFR(6)
  x0 += ks0; x1 += ks1 + 3u;
  TFR(17) TFR(29) TFR(16) TFR(24)
  x0 += ks1; x1 += ks2 + 4u;
  TFR(13) TFR(15) TFR(26) TFR(6)
  x0 += ks2; x1 += ks0 + 5u;
#undef TFR
  o0 = x0; o1 = x1;
}

__device__ __forceinline__ unsigned rng_bits(unsigned j) {
  unsigned a, b;
  tf2x32(0u, j, a, b);
  return a ^ b;
}

__device__ __forceinline__ float u01(unsigned bits) {
  return __uint_as_float((bits >> 9) | 0x3f800000u) - 1.0f;
}

// ---------------- node projection + zero-init of topk control words
__global__ __launch_bounds__(256) void precompute_ab(
    const float* __restrict__ feats, const float* __restrict__ W_out,
    float* __restrict__ A, float* __restrict__ B,
    unsigned* __restrict__ cnt, unsigned* __restrict__ done) {
  int row = blockIdx.x * 4 + (threadIdx.x >> 6);   // h*N + n
  int d = threadIdx.x & 63;
  if (blockIdx.x == 0) {            // ws is poisoned 0xAA each call: zero control
    if (threadIdx.x < 4) cnt[threadIdx.x] = 0u;
    else if (threadIdx.x < 8) done[threadIdx.x - 4] = 0u;
  }
  __shared__ float f[4][64];
  f[threadIdx.x >> 6][d] = feats[row * D_ + d];
  __syncthreads();
  const float* fr = f[threadIdx.x >> 6];
  float a = 0.f, b = 0.f;
#pragma unroll 8
  for (int k = 0; k < D_; ++k) {
    float fv = fr[k];
    a = fmaf(fv, W_out[k * D_ + d], a);          // sender rows [0,64)
    b = fmaf(fv, W_out[(k + D_) * D_ + d], b);   // receiver rows [64,128)
  }
  A[row * D_ + d] = a;
  B[row * D_ + d] = b;
}

// ---------------- edge kernel: 64 snd x 16 rec tile, 4 edges/thread.
// LDS ~22 KB, launch_bounds(256,4) -> 4 blocks/CU: hides threefry/logf latency.
// NO grid-wide rendezvous (R4 cooperative launch failed; R6 manual spin cost
// ~75 us in atomic contention) — kernel boundaries are the cheap barrier.
__global__ __launch_bounds__(256, 4) void edge_kernel(
    const float* __restrict__ A, const float* __restrict__ B,
    const float* __restrict__ b_out, const float* __restrict__ W_cat,
    const float* __restrict__ b_cat, float* __restrict__ out,
    unsigned long long* __restrict__ blockmax) {
  __shared__ __align__(16) float Ash[64][68];   // stride 68: rows 16B-aligned
  __shared__ __align__(16) float Bsh[16][64];
  __shared__ float4 bsh4[16];
  __shared__ float4 wc4[32];
  __shared__ float bc2[2];
  __shared__ unsigned long long wmax[4];

  const int t = threadIdx.x;
  const int h = blockIdx.z;
  const int snd_base = blockIdx.x * 64;
  const int rec_base = blockIdx.y * 16;

  {
    const float4* A4 = (const float4*)(A + (h * N_ + snd_base) * D_);
    for (int i = t; i < 1024; i += 256)          // 64 rows x 16 float4
      *(float4*)&Ash[i >> 4][(i & 15) << 2] = A4[i];
    const float4* B4 = (const float4*)(B + (h * N_ + rec_base) * D_);
    *(float4*)&Bsh[t >> 4][(t & 15) << 2] = B4[t];
  }
  if (t < 16) bsh4[t] = ((const float4*)b_out)[t];
  else if (t < 48) wc4[t - 16] = ((const float4*)W_cat)[t - 16];
  else if (t == 48) { bc2[0] = b_cat[0]; bc2[1] = b_cat[1]; }
  __syncthreads();

  const int s = t & 63;            // sender lane (per-lane varying)
  const int rg = (t >> 6) * 4;     // receiver group (wave-uniform)

  float l0[4], l1[4];
#pragma unroll
  for (int r = 0; r < 4; ++r) { l0[r] = 0.f; l1[r] = 0.f; }

  // Per edge the fp chain is EXACTLY: for d=0..63 { t=relu((A+B)+b); l=fma(t,w,l) }
#pragma unroll
  for (int d4 = 0; d4 < 16; ++d4) {
    const float4 a0 = *(const float4*)&Ash[s][d4 << 2];
    const float4 bd = bsh4[d4];
    const float4 wA = wc4[2 * d4];
    const float4 wB = wc4[2 * d4 + 1];
#pragma unroll
    for (int r = 0; r < 4; ++r) {
      const float4 bv = *(const float4*)&Bsh[rg + r][d4 << 2];
      float t0;
      t0 = fmaxf((a0.x + bv.x) + bd.x, 0.f);
      l0[r] = fmaf(t0, wA.x, l0[r]); l1[r] = fmaf(t0, wA.y, l1[r]);
      t0 = fmaxf((a0.y + bv.y) + bd.y, 0.f);
      l0[r] = fmaf(t0, wA.z, l0[r]); l1[r] = fmaf(t0, wA.w, l1[r]);
      t0 = fmaxf((a0.z + bv.z) + bd.z, 0.f);
      l0[r] = fmaf(t0, wB.x, l0[r]); l1[r] = fmaf(t0, wB.y, l1[r]);
      t0 = fmaxf((a0.w + bv.w) + bd.w, 0.f);
      l0[r] = fmaf(t0, wB.z, l0[r]); l1[r] = fmaf(t0, wB.w, l1[r]);
    }
  }

  unsigned long long mk = 0ull;
#pragma unroll
  for (int r = 0; r < 4; ++r) {
    float L0 = l0[r] + bc2[0];
    float L1 = l1[r] + bc2[1];
    const unsigned snd = (unsigned)(snd_base + s);
    const unsigned rec = (unsigned)(rec_base + rg + r);
    const unsigned e = rec * (unsigned)N_ + snd;
    const unsigned base = ((unsigned)h << 18) + e;
    const unsigned j0 = base * 2u;

    float uu0 = u01(rng_bits(j0));
    float uu1 = u01(rng_bits(j0 + 1u));
    float g0 = -logf(-logf(uu0 + EPS_) + EPS_);
    float g1 = -logf(-logf(uu1 + EPS_) + EPS_);

    // argmax(softmax((l+g)/0.5)) == (L1+g1 > L0+g0): /0.5 exact, softmax monotone
    float cm = ((L1 + g1) > (L0 + g0)) ? 1.0f : 0.0f;

    float lm = fmaxf(L0, L1);
    float p0 = expf(L0 - lm), p1 = expf(L1 - lm);
    float pr = p1 / (p0 + p1);

    out[base] = cm;
    out[HE_ + base] = pr;

    unsigned long long key =
        ((unsigned long long)__float_as_uint(pr) << 32) | (unsigned)(~e);
    mk = key > mk ? key : mk;
  }

  // vectorized zero of this tile's sparse region (16 rows x 64 cols, disjoint
  // 256B runs; proven in R6) — winners are set later by topk_fused.
  {
    const float4 z4 = {0.f, 0.f, 0.f, 0.f};
    *(float4*)&out[2u * HE_ + ((unsigned)h << 18) +
                   (unsigned)(rec_base + (t >> 4)) * N_ + (unsigned)snd_base +
                   ((unsigned)(t & 15) << 2)] = z4;
  }

#pragma unroll
  for (int off = 32; off; off >>= 1) {
    unsigned long long o = __shfl_xor(mk, off, 64);
    mk = o > mk ? o : mk;
  }
  if ((t & 63) == 0) wmax[t >> 6] = mk;
  __syncthreads();
  if (t == 0) {
    unsigned long long m = wmax[0];
#pragma unroll
    for (int i = 1; i < 4; ++i) m = wmax[i] > m ? wmax[i] : m;
    blockmax[h * 256 + blockIdx.y * gridDim.x + blockIdx.x] = m;  // 256 chunks/head
  }
}

// ---------------- fused top-k: inline threshold + compact + last-block finish
__global__ __launch_bounds__(512) void topk_fused(
    const float* __restrict__ prob, const unsigned long long* __restrict__ blockmax,
    unsigned* __restrict__ cnt, unsigned* __restrict__ done,
    unsigned long long* __restrict__ cand, float* __restrict__ sparse) {
  __shared__ unsigned long long keys[512];
  __shared__ unsigned long long thrS;
  __shared__ unsigned tkS;
  const int t = threadIdx.x, h = blockIdx.y, blk = blockIdx.x;

  // phase 1: threshold = 64th-largest of the 256 chunk maxes (exact; keys unique)
  if (t < 256) keys[t] = blockmax[h * 256 + t];
  __syncthreads();
  if (t < 256) {
    unsigned long long my = keys[t];
    int rank = 0;
    for (int j = 0; j < 256; ++j) rank += (keys[j] > my);
    if (rank == 63) thrS = my;     // guaranteed <= true 64th-largest element key
  }
  __syncthreads();
  const unsigned long long thr = thrS;

  // phase 2: scan this block's 4096 probs (8/thread, coalesced float4)
  const unsigned seg = (unsigned)blk * 4096u;
#pragma unroll
  for (int i = 0; i < 2; ++i) {
    const unsigned e0 = seg + (unsigned)i * 2048u + (unsigned)t * 4u;
    float4 p = *(const float4*)(prob + (unsigned)h * E_ + e0);
    float pv[4] = {p.x, p.y, p.z, p.w};
#pragma unroll
    for (int k2 = 0; k2 < 4; ++k2) {
      unsigned e = e0 + (unsigned)k2;
      unsigned long long key =
          ((unsigned long long)__float_as_uint(pv[k2]) << 32) | (unsigned)(~e);
      if (key >= thr) {
        unsigned pos = atomicAdd(&cnt[h], 1u);    // expected total ~155 << 512
        if (pos < 512u) cand[h * 512 + pos] = key;
      }
    }
  }
  __syncthreads();
  if (t == 0) { __threadfence(); tkS = atomicAdd(&done[h], 1u); }  // release
  __syncthreads();

  // phase 3: last block per head sorts candidates, scatters 64 ones
  if (tkS == 63u) {
    if (t == 0) __threadfence();                  // acquire
    __syncthreads();
    unsigned n = atomicAdd(&cnt[h], 0u);          // coherent read of final count
    if (n > 512u) n = 512u;
    keys[t] = (t < (int)n) ? cand[h * 512 + t] : 0ull;
    __syncthreads();
    for (int k = 2; k <= 512; k <<= 1)
      for (int j = k >> 1; j > 0; j >>= 1) {
        int ixj = t ^ j;
        if (ixj > t) {
          unsigned long long a = keys[t], b = keys[ixj];
          bool up = (t & k) == 0;
          if ((a > b) == up) { keys[t] = b; keys[ixj] = a; }
        }
        __syncthreads();
      }
    if (t >= 448) {                               // top 64 of ascending sort
      unsigned e = ~(unsigned)(keys[t] & 0xFFFFFFFFull);
      if (e < (unsigned)E_) sparse[(unsigned)h * E_ + e] = 1.0f;
    }
  }
}

extern "C" void kernel_launch(void* const* d_in, const int* in_sizes, int n_in,
                              void* d_out, int out_size, void* d_ws, size_t ws_size,
                              hipStream_t stream) {
  const float* feats = (const float*)d_in[0];
  const float* W_out = (const float*)d_in[1];
  const float* b_out = (const float*)d_in[2];
  const float* W_cat = (const float*)d_in[3];
  const float* b_cat = (const float*)d_in[4];
  float* out = (float*)d_out;

  // workspace: A | B | blockmax | cand | cnt | done
  float* A = (float*)d_ws;
  float* B = A + H_ * N_ * D_;
  unsigned long long* blockmax = (unsigned long long*)(B + H_ * N_ * D_);
  unsigned long long* cand = blockmax + H_ * 256;
  unsigned* cnt = (unsigned*)(cand + H_ * 512);
  unsigned* done = cnt + H_;

  precompute_ab<<<dim3(H_ * N_ / 4), dim3(256), 0, stream>>>(feats, W_out, A, B,
                                                             cnt, done);
  edge_kernel<<<dim3(N_ / 64, N_ / 16, H_), dim3(256), 0, stream>>>(
      A, B, b_out, W_cat, b_cat, out, blockmax);
  topk_fused<<<dim3(64, H_), dim3(512), 0, stream>>>(out + HE_, blockmax, cnt,
                                                     done, cand, out + 2 * HE_);
}